// Round 4
// baseline (4916.925 us; speedup 1.0000x reference)
//
#include <hip/hip_runtime.h>
#include <math.h>

#define NA 512
#define NN (NA*NA)
#define COULOMB 14.399645478425668f
#define SQRT_PI 1.7724538509055160273f

__device__ __forceinline__ float rl(float x, int lane) {
    return __int_as_float(__builtin_amdgcn_readlane(__float_as_int(x), lane));
}

__device__ __forceinline__ float pair_val(float dx, float dy, float dz,
                                          float s2i, float s2k) {
    float d2 = dx*dx + dy*dy + dz*dz;
    float rinv = rsqrtf(d2);
    return COULOMB * erff(d2 * rinv * rsqrtf(2.f * (s2i + s2k))) * rinv;
}

// ---------------------------------------------------------------- K1: per-atom
__global__ void k_pre(const float* __restrict__ feats, const float* __restrict__ w,
                      const int* __restrict__ type, const float* __restrict__ hard,
                      const float* __restrict__ sigma,
                      float* __restrict__ chi, float* __restrict__ diag,
                      float* __restrict__ sigA, int N) {
    __shared__ float wl[64];
    int tid = threadIdx.x;
    if (tid < 64) wl[tid] = w[tid];
    __syncthreads();
    int i = blockIdx.x * 256 + tid;
    if (i >= N) return;
    const float4* fp = (const float4*)(feats + (size_t)i * 64);
    float acc = 0.f;
#pragma unroll
    for (int q = 0; q < 16; q++) {
        float4 v = fp[q];
        acc += v.x * wl[4*q] + v.y * wl[4*q+1] + v.z * wl[4*q+2] + v.w * wl[4*q+3];
    }
    chi[i] = acc;
    int t = type[i];
    float s = sigma[t];
    float h = hard[t];
    sigA[i] = s;
    diag[i] = h * h + COULOMB / (SQRT_PI * s);
}

// ---------------------------------------------------------------- fused left-looking Cholesky
// One block (512 thr) per molecule, one dispatch. Per round j:
//   U: generate col-block [jb..511]x[jb..jb+64) via erf, subtract all prior panels
//      (K accumulated in registers; trailing RMW traffic eliminated), store.
//   A/A2/B/B2/C: round-3-proven diag factor + row-owned trsm.
// VGPR demand audited: U dual-supertile ~150, C ~100; cap 256 via (512,2). No spills.
#define QEQ_STEP2(COMP, KOF) \
  { const int kcol = k4*4 + KOF; \
    float b0 = Bsh[(cg*4+0)*65 + kcol]; \
    float b1 = Bsh[(cg*4+1)*65 + kcol]; \
    float b2 = Bsh[(cg*4+2)*65 + kcol]; \
    float b3 = Bsh[(cg*4+3)*65 + kcol]; \
    _Pragma("unroll") \
    for (int rr = 0; rr < 8; rr++) { \
      accA[rr][0] = fmaf(-a0[rr].COMP, b0, accA[rr][0]); \
      accA[rr][1] = fmaf(-a0[rr].COMP, b1, accA[rr][1]); \
      accA[rr][2] = fmaf(-a0[rr].COMP, b2, accA[rr][2]); \
      accA[rr][3] = fmaf(-a0[rr].COMP, b3, accA[rr][3]); \
      accB[rr][0] = fmaf(-a1[rr].COMP, b0, accB[rr][0]); \
      accB[rr][1] = fmaf(-a1[rr].COMP, b1, accB[rr][1]); \
      accB[rr][2] = fmaf(-a1[rr].COMP, b2, accB[rr][2]); \
      accB[rr][3] = fmaf(-a1[rr].COMP, b3, accB[rr][3]); \
    } }

#define QEQ_STEP1(COMP, KOF) \
  { const int kcol = k4*4 + KOF; \
    float b0 = Bsh[(cg*4+0)*65 + kcol]; \
    float b1 = Bsh[(cg*4+1)*65 + kcol]; \
    float b2 = Bsh[(cg*4+2)*65 + kcol]; \
    float b3 = Bsh[(cg*4+3)*65 + kcol]; \
    _Pragma("unroll") \
    for (int rr = 0; rr < 8; rr++) { \
      accA[rr][0] = fmaf(-a0[rr].COMP, b0, accA[rr][0]); \
      accA[rr][1] = fmaf(-a0[rr].COMP, b1, accA[rr][1]); \
      accA[rr][2] = fmaf(-a0[rr].COMP, b2, accA[rr][2]); \
      accA[rr][3] = fmaf(-a0[rr].COMP, b3, accA[rr][3]); \
    } }

__global__ void __launch_bounds__(512, 2) k_chol(const float* __restrict__ pos,
                                                 const float* __restrict__ sigA,
                                                 const float* __restrict__ diagA,
                                                 float* __restrict__ C) {
    const int b = blockIdx.x;
    float* __restrict__ Cb = C + (size_t)b * NN;
    const int tid = threadIdx.x;
    __shared__ float px[NA], py[NA], pz[NA], s2s[NA], dgs[NA];
    __shared__ float D[64 * 65];
    __shared__ float DT[64 * 64];
    __shared__ float Bsh[64 * 65];
    __shared__ float invd[64];

    {
        px[tid] = pos[((size_t)b * NA + tid) * 3 + 0];
        py[tid] = pos[((size_t)b * NA + tid) * 3 + 1];
        pz[tid] = pos[((size_t)b * NA + tid) * 3 + 2];
        float s = sigA[b * NA + tid];
        s2s[tid] = s * s;
        dgs[tid] = diagA[b * NA + tid];
    }
    __syncthreads();

    const int rg = tid >> 4;        // 0..31 row-groups of 8
    const int cg = tid & 15;        // 0..15 col-groups of 4

    for (int j = 0; j < 8; j++) {
        const int jb = j * 64;
        const int mp = NA - jb;     // rows in col-block (multiple of 64)
        const bool vA = (rg * 8) < mp;
        const bool vB = (256 + rg * 8) < mp;

        // ================= Phase U: generate + update block-column j =================
        float accA[8][4], accB[8][4];
#pragma unroll
        for (int rr = 0; rr < 8; rr++) {
            const int gi0 = jb + rg * 8 + rr;
            const int gi1 = gi0 + 256;
#pragma unroll
            for (int cc = 0; cc < 4; cc++) {
                const int gc = jb + cg * 4 + cc;
                float v0 = 0.f, v1 = 0.f;
                if (vA) v0 = (gi0 == gc) ? dgs[gi0]
                        : pair_val(px[gi0]-px[gc], py[gi0]-py[gc], pz[gi0]-pz[gc],
                                   s2s[gi0], s2s[gc]);
                if (vB) v1 = (gi1 == gc) ? dgs[gi1]
                        : pair_val(px[gi1]-px[gc], py[gi1]-py[gc], pz[gi1]-pz[gc],
                                   s2s[gi1], s2s[gc]);
                accA[rr][cc] = v0;
                accB[rr][cc] = v1;
            }
        }

        for (int kb = 0; kb < j; kb++) {
            __syncthreads();
            // stage B-slab: L[jb+c, kb*64 + k]  (final L from earlier rounds)
#pragma unroll
            for (int e = 0; e < 2; e++) {
                int f = e * 512 + tid;
                int rw = f >> 4, s = f & 15;
                float4 v = *(const float4*)(Cb + (size_t)(jb + rw) * NA + kb * 64 + s * 4);
                Bsh[rw * 65 + s * 4 + 0] = v.x;
                Bsh[rw * 65 + s * 4 + 1] = v.y;
                Bsh[rw * 65 + s * 4 + 2] = v.z;
                Bsh[rw * 65 + s * 4 + 3] = v.w;
            }
            __syncthreads();
            if (mp > 256) {
#pragma unroll 4
                for (int k4 = 0; k4 < 16; k4++) {
                    float4 a0[8], a1[8];
#pragma unroll
                    for (int rr = 0; rr < 8; rr++) {
                        a0[rr] = vA ? *(const float4*)(Cb + (size_t)(jb + rg*8 + rr) * NA + kb*64 + k4*4)
                                    : make_float4(0.f,0.f,0.f,0.f);
                        a1[rr] = vB ? *(const float4*)(Cb + (size_t)(jb + 256 + rg*8 + rr) * NA + kb*64 + k4*4)
                                    : make_float4(0.f,0.f,0.f,0.f);
                    }
                    QEQ_STEP2(x, 0) QEQ_STEP2(y, 1) QEQ_STEP2(z, 2) QEQ_STEP2(w, 3)
                }
            } else {
#pragma unroll 4
                for (int k4 = 0; k4 < 16; k4++) {
                    float4 a0[8];
#pragma unroll
                    for (int rr = 0; rr < 8; rr++) {
                        a0[rr] = vA ? *(const float4*)(Cb + (size_t)(jb + rg*8 + rr) * NA + kb*64 + k4*4)
                                    : make_float4(0.f,0.f,0.f,0.f);
                    }
                    QEQ_STEP1(x, 0) QEQ_STEP1(y, 1) QEQ_STEP1(z, 2) QEQ_STEP1(w, 3)
                }
            }
        }

        // store block-column (float4 per rr)
#pragma unroll
        for (int rr = 0; rr < 8; rr++) {
            if (vA)
                *(float4*)(Cb + (size_t)(jb + rg*8 + rr) * NA + jb + cg*4) =
                    make_float4(accA[rr][0], accA[rr][1], accA[rr][2], accA[rr][3]);
            if (vB)
                *(float4*)(Cb + (size_t)(jb + 256 + rg*8 + rr) * NA + jb + cg*4) =
                    make_float4(accB[rr][0], accB[rr][1], accB[rr][2], accB[rr][3]);
        }
        __threadfence();
        __syncthreads();

        // ================= Phase A: load diag tile =================
#pragma unroll
        for (int e = 0; e < 8; e++) {
            int f = e * 512 + tid;
            int rr = f >> 6, cc = f & 63;
            D[rr * 65 + cc] = Cb[(size_t)(jb + rr) * NA + jb + cc];
        }

        // ---- Phase A2: panel row preload (rows on tid 64..)
        const int m = mp - 64;
        float rv[64];
        const int r = tid - 64;
        if (r >= 0 && r < m) {
            const float4* rp = (const float4*)(Cb + (size_t)(jb + 64 + r) * NA + jb);
#pragma unroll
            for (int q = 0; q < 16; q++) {
                float4 v = rp[q];
                rv[4*q] = v.x; rv[4*q+1] = v.y; rv[4*q+2] = v.z; rv[4*q+3] = v.w;
            }
        }
        __syncthreads();

        // ---- Phase B: wave 0 register-resident symmetric elimination
        if (tid < 64) {
            const int t = tid;
            float cl[64];
#pragma unroll
            for (int i = 0; i < 64; i++) cl[i] = (i >= t) ? D[i * 65 + t] : D[t * 65 + i];
#pragma unroll
            for (int k = 0; k < 64; k++) {
                float pivot = rl(cl[k], k);
                float invp = 1.0f / pivot;
                float factor = (t > k) ? (cl[k] * invp) : 0.0f;
#pragma unroll
                for (int i = k + 1; i < 64; i++) {
                    float bc = rl(cl[i], k);
                    cl[i] -= bc * factor;
                }
            }
            float rs = 1.0f / sqrtf(cl[t]);
            invd[t] = rs;
#pragma unroll
            for (int i = 0; i < 64; i++)
                if (i >= t) D[i * 65 + t] = cl[i] * rs;
        }
        __syncthreads();

        // ---- Phase B2: build DT + store L diag (lower)
#pragma unroll
        for (int e = 0; e < 8; e++) {
            int f = e * 512 + tid;
            int row = f >> 6, cc = f & 63;
            float v = D[row * 65 + cc];
            DT[row * 64 + cc] = (cc < row) ? v : 0.f;
            if (cc <= row) Cb[(size_t)(jb + row) * NA + jb + cc] = v;
        }
        __syncthreads();

        // ---- Phase C: row-owned trsm, store L21 panel
        if (r >= 0 && r < m) {
#pragma unroll
            for (int k = 0; k < 64; k++) {
                float acc = rv[k];
                const float4* Lr = (const float4*)(DT + k * 64);
                const int k4 = k >> 2;
#pragma unroll
                for (int t4 = 0; t4 < k4; t4++) {
                    float4 Lv = Lr[t4];
                    acc -= Lv.x * rv[4*t4] + Lv.y * rv[4*t4+1] + Lv.z * rv[4*t4+2] + Lv.w * rv[4*t4+3];
                }
#pragma unroll
                for (int tt = k4 * 4; tt < k; tt++) acc -= DT[k * 64 + tt] * rv[tt];
                rv[k] = acc * invd[k];
            }
            float4* rp = (float4*)(Cb + (size_t)(jb + 64 + r) * NA + jb);
#pragma unroll
            for (int q = 0; q < 16; q++)
                rp[q] = make_float4(rv[4*q], rv[4*q+1], rv[4*q+2], rv[4*q+3]);
        }
        __threadfence();
        __syncthreads();
    }
}

// ---------------------------------------------------------------- K3: solve + outputs
// Update-form substitution: forward = coalesced row reads (8 lanes/row, float4);
// backward = row-contiguous axpy with LDS partial sums. Both RHS together.
__global__ void __launch_bounds__(512, 2) k_solve(const float* __restrict__ C,
                                                  const float* __restrict__ chiA,
                                                  const float* __restrict__ Qtot,
                                                  float* __restrict__ out, int B) {
    int b = blockIdx.x;
    const float* Cb = C + (size_t)b * NN;
    int tid = threadIdx.x;
    __shared__ float D[64 * 65];
    __shared__ float r1[NA], r2[NA];
    __shared__ float pb1[4][NA], pb2[4][NA];
    __shared__ float red[16];
    __shared__ float muS;

    r1[tid] = chiA[b * NA + tid];
    r2[tid] = 1.0f;

    const int sub = tid & 7;        // forward: 8 lanes per row
    const int rowg = tid >> 3;

    // -------- forward: L y = r
    for (int j = 0; j < 8; j++) {
        const int jb = j * 64;
        __syncthreads();
#pragma unroll
        for (int e = 0; e < 8; e++) {
            int f = e * 512 + tid;
            int row = f >> 6, cc = f & 63;
            D[row * 65 + cc] = Cb[(size_t)(jb + row) * NA + jb + cc];
        }
        __syncthreads();
        // triangular solve on r[jb..jb+63], both RHS (waves 0/1)
        if (tid < 128) {
            int lane = tid & 63;
            float* vv = (tid < 64) ? r1 : r2;
            float val = vv[jb + lane];
            float idg = 1.0f / D[lane * 65 + lane];
#pragma unroll
            for (int k = 0; k < 64; k++) {
                float yk = rl(val, k) * rl(idg, k);
                if (lane == k) vv[jb + k] = yk;
                float lv = (lane > k) ? D[lane * 65 + k] : 0.f;
                val -= lv * yk;
            }
        }
        __syncthreads();
        // rank-64 update of remaining residual rows
#pragma unroll
        for (int p = 0; p < 7; p++) {
            int g = jb + 64 + p * 64 + rowg;
            if (g < NA) {
                const float4* Lr = (const float4*)(Cb + (size_t)g * NA + jb + sub * 8);
                float4 a0 = Lr[0], a1 = Lr[1];
                int y0 = jb + sub * 8;
                float d1 = a0.x*r1[y0]   + a0.y*r1[y0+1] + a0.z*r1[y0+2] + a0.w*r1[y0+3]
                         + a1.x*r1[y0+4] + a1.y*r1[y0+5] + a1.z*r1[y0+6] + a1.w*r1[y0+7];
                float d2 = a0.x*r2[y0]   + a0.y*r2[y0+1] + a0.z*r2[y0+2] + a0.w*r2[y0+3]
                         + a1.x*r2[y0+4] + a1.y*r2[y0+5] + a1.z*r2[y0+6] + a1.w*r2[y0+7];
                d1 += __shfl_xor(d1, 1); d2 += __shfl_xor(d2, 1);
                d1 += __shfl_xor(d1, 2); d2 += __shfl_xor(d2, 2);
                d1 += __shfl_xor(d1, 4); d2 += __shfl_xor(d2, 4);
                if (sub == 0) { r1[g] -= d1; r2[g] -= d2; }
            }
        }
    }

    // -------- backward: L^T x = y
    const int ii = tid & 127;       // float4 column chunk
    const int gg = tid >> 7;        // 0..3, 16 g's each
    for (int j = 7; j >= 0; j--) {
        const int jb = j * 64;
        __syncthreads();
#pragma unroll
        for (int e = 0; e < 8; e++) {
            int f = e * 512 + tid;
            int row = f >> 6, cc = f & 63;
            D[row * 65 + cc] = Cb[(size_t)(jb + row) * NA + jb + cc];
        }
        __syncthreads();
        if (tid < 128) {
            int lane = tid & 63;
            float* vv = (tid < 64) ? r1 : r2;
            float val = vv[jb + lane];
            float idg = 1.0f / D[lane * 65 + lane];
#pragma unroll
            for (int k = 63; k >= 0; k--) {
                float xk = rl(val, k) * rl(idg, k);
                if (lane == k) vv[jb + k] = xk;
                float lv = (lane < k) ? D[k * 65 + lane] : 0.f;
                val -= lv * xk;
            }
        }
        __syncthreads();
        if (jb > 0) {
            const int nf4 = jb >> 2;
            float4 s1 = make_float4(0.f,0.f,0.f,0.f), s2 = make_float4(0.f,0.f,0.f,0.f);
            if (ii < nf4) {
#pragma unroll
                for (int gq = 0; gq < 16; gq++) {
                    int g = jb + gg * 16 + gq;
                    float x1 = r1[g], x2 = r2[g];
                    float4 Lv = *(const float4*)(Cb + (size_t)g * NA + ii * 4);
                    s1.x += Lv.x * x1; s1.y += Lv.y * x1; s1.z += Lv.z * x1; s1.w += Lv.w * x1;
                    s2.x += Lv.x * x2; s2.y += Lv.y * x2; s2.z += Lv.z * x2; s2.w += Lv.w * x2;
                }
            }
            *(float4*)(&pb1[gg][ii * 4]) = s1;
            *(float4*)(&pb2[gg][ii * 4]) = s2;
            __syncthreads();
            if (tid < jb) {
                r1[tid] -= pb1[0][tid] + pb1[1][tid] + pb1[2][tid] + pb1[3][tid];
                r2[tid] -= pb2[0][tid] + pb2[1][tid] + pb2[2][tid] + pb2[3][tid];
            }
        }
    }
    __syncthreads();

    // -------- mu, q, energy: e = 0.5*chi'q - 0.5*mu*Q
    float s1p = r1[tid], s2p = r2[tid];
#pragma unroll
    for (int off = 1; off < 64; off <<= 1) {
        s1p += __shfl_xor(s1p, off);
        s2p += __shfl_xor(s2p, off);
    }
    if ((tid & 63) == 0) { red[tid >> 6] = s1p; red[8 + (tid >> 6)] = s2p; }
    __syncthreads();
    if (tid == 0) {
        float s1 = 0.f, s2 = 0.f;
#pragma unroll
        for (int wv = 0; wv < 8; wv++) { s1 += red[wv]; s2 += red[8 + wv]; }
        muS = -(Qtot[b] + s1) / s2;
    }
    __syncthreads();
    float mu = muS;
    float qv = -r1[tid] - mu * r2[tid];
    out[B + (size_t)b * NA + tid] = qv;

    float eacc = chiA[b * NA + tid] * qv;
#pragma unroll
    for (int off = 1; off < 64; off <<= 1) eacc += __shfl_xor(eacc, off);
    __syncthreads();
    if ((tid & 63) == 0) red[tid >> 6] = eacc;
    __syncthreads();
    if (tid == 0) {
        float e = 0.f;
#pragma unroll
        for (int wv = 0; wv < 8; wv++) e += red[wv];
        out[b] = 0.5f * e - 0.5f * mu * Qtot[b];
    }
}

// ---------------------------------------------------------------- host launch
extern "C" void kernel_launch(void* const* d_in, const int* in_sizes, int n_in,
                              void* d_out, int out_size, void* d_ws, size_t ws_size,
                              hipStream_t stream) {
    const int B = in_sizes[3];          // 128 molecules
    const int N = in_sizes[2];          // 65536 atoms
    const float* feats = (const float*)d_in[0];
    const float* pos   = (const float*)d_in[1];
    const int*   type  = (const int*)d_in[2];
    const float* Qt    = (const float*)d_in[3];
    const float* w     = (const float*)d_in[4];
    const float* hard  = (const float*)d_in[5];
    const float* sig   = (const float*)d_in[6];
    float* out = (float*)d_out;
    float* ws  = (float*)d_ws;

    float* C    = ws;                       // B * 512 * 512 (holds L; upper never touched)
    float* chi  = ws + (size_t)B * NN;      // N
    float* diag = chi + N;                  // N
    float* sigA = diag + N;                 // N

    k_pre<<<(N + 255) / 256, 256, 0, stream>>>(feats, w, type, hard, sig, chi, diag, sigA, N);
    k_chol<<<B, 512, 0, stream>>>(pos, sigA, diag, C);
    k_solve<<<B, 512, 0, stream>>>(C, chi, Qt, out, B);
}

// Round 5
// 1707.263 us; speedup vs baseline: 2.8800x; 2.8800x over previous
//
#include <hip/hip_runtime.h>
#include <math.h>

#define NA 512
#define NN (NA*NA)
#define COULOMB 14.399645478425668f
#define SQRT_PI 1.7724538509055160273f

__device__ __forceinline__ float rl(float x, int lane) {
    return __int_as_float(__builtin_amdgcn_readlane(__float_as_int(x), lane));
}

__device__ __forceinline__ float pair_val(float dx, float dy, float dz,
                                          float s2i, float s2k) {
    float d2 = dx*dx + dy*dy + dz*dz;
    float rinv = rsqrtf(d2);
    return COULOMB * erff(d2 * rinv * rsqrtf(2.f * (s2i + s2k))) * rinv;
}

// ---------------------------------------------------------------- K1: per-atom
__global__ void k_pre(const float* __restrict__ feats, const float* __restrict__ w,
                      const int* __restrict__ type, const float* __restrict__ hard,
                      const float* __restrict__ sigma,
                      float* __restrict__ chi, float* __restrict__ diag,
                      float* __restrict__ sigA, int N) {
    __shared__ float wl[64];
    int tid = threadIdx.x;
    if (tid < 64) wl[tid] = w[tid];
    __syncthreads();
    int i = blockIdx.x * 256 + tid;
    if (i >= N) return;
    const float4* fp = (const float4*)(feats + (size_t)i * 64);
    float acc = 0.f;
#pragma unroll
    for (int q = 0; q < 16; q++) {
        float4 v = fp[q];
        acc += v.x * wl[4*q] + v.y * wl[4*q+1] + v.z * wl[4*q+2] + v.w * wl[4*q+3];
    }
    chi[i] = acc;
    int t = type[i];
    float s = sigma[t];
    float h = hard[t];
    sigA[i] = s;
    diag[i] = h * h + COULOMB / (SQRT_PI * s);
}

// ---------------------------------------------------------------- fused left-looking Cholesky
// One block (512 thr) per molecule. Per round j: phase U generates block-column j
// by erf and subtracts prior panels, processed in ROW-CHUNKS of 256 so per-thread
// register demand stays ~100 (acc[8][4]=32 + a[8] float4=32 + addressing) — fits
// even a 128-VGPR cap; round-4's dual-supertile (demand ~200) spilled at cap 128.
// Chunk 0 also deposits the diag tile into LDS D, removing phase A entirely.
__global__ void __launch_bounds__(512, 1) k_chol(const float* __restrict__ pos,
                                                 const float* __restrict__ sigA,
                                                 const float* __restrict__ diagA,
                                                 float* __restrict__ C) {
    const int b = blockIdx.x;
    float* __restrict__ Cb = C + (size_t)b * NN;
    const int tid = threadIdx.x;
    __shared__ float px[NA], py[NA], pz[NA], s2s[NA], dgs[NA];
    __shared__ float D[64 * 65];
    __shared__ float DT[64 * 64];
    __shared__ float Bsh[64 * 65];
    __shared__ float invd[64];

    {
        px[tid] = pos[((size_t)b * NA + tid) * 3 + 0];
        py[tid] = pos[((size_t)b * NA + tid) * 3 + 1];
        pz[tid] = pos[((size_t)b * NA + tid) * 3 + 2];
        float s = sigA[b * NA + tid];
        s2s[tid] = s * s;
        dgs[tid] = diagA[b * NA + tid];
    }
    __syncthreads();

    const int rg = tid >> 4;        // 0..31 row-groups of 8
    const int cg = tid & 15;        // 0..15 col-groups of 4

    for (int j = 0; j < 8; j++) {
        const int jb = j * 64;
        const int mp = NA - jb;             // rows in col-block (multiple of 64)
        const int nch = (mp + 255) >> 8;    // 1 or 2 chunks of 256 rows

        // ================= Phase U: generate + update block-column j =================
        for (int ch = 0; ch < nch; ch++) {
            const int rbase = ch * 256 + rg * 8;     // chunk-local row base
            const bool vA = rbase < mp;
            const int gi0 = jb + rbase;              // global row of rr=0

            float acc[8][4];
#pragma unroll
            for (int rr = 0; rr < 8; rr++) {
                const int gi = gi0 + rr;
#pragma unroll
                for (int cc = 0; cc < 4; cc++) {
                    const int gc = jb + cg * 4 + cc;
                    float v = 0.f;
                    if (vA) v = (gi == gc) ? dgs[gi]
                            : pair_val(px[gi]-px[gc], py[gi]-py[gc], pz[gi]-pz[gc],
                                       s2s[gi], s2s[gc]);
                    acc[rr][cc] = v;
                }
            }

            for (int kb = 0; kb < j; kb++) {
                __syncthreads();
                // stage B-slab: L[jb+c, kb*64+k] (final L from earlier rounds)
#pragma unroll
                for (int e = 0; e < 2; e++) {
                    int f = e * 512 + tid;
                    int rw = f >> 4, s = f & 15;
                    float4 v = *(const float4*)(Cb + (size_t)(jb + rw) * NA + kb * 64 + s * 4);
                    Bsh[rw * 65 + s * 4 + 0] = v.x;
                    Bsh[rw * 65 + s * 4 + 1] = v.y;
                    Bsh[rw * 65 + s * 4 + 2] = v.z;
                    Bsh[rw * 65 + s * 4 + 3] = v.w;
                }
                __syncthreads();
#pragma unroll 2
                for (int k4 = 0; k4 < 16; k4++) {
                    float4 a[8];
#pragma unroll
                    for (int rr = 0; rr < 8; rr++)
                        a[rr] = vA ? *(const float4*)(Cb + (size_t)(gi0 + rr) * NA + kb*64 + k4*4)
                                   : make_float4(0.f, 0.f, 0.f, 0.f);
#pragma unroll
                    for (int kof = 0; kof < 4; kof++) {
                        const int kcol = k4 * 4 + kof;
                        float b0 = Bsh[(cg*4+0)*65 + kcol];
                        float b1 = Bsh[(cg*4+1)*65 + kcol];
                        float b2 = Bsh[(cg*4+2)*65 + kcol];
                        float b3 = Bsh[(cg*4+3)*65 + kcol];
#pragma unroll
                        for (int rr = 0; rr < 8; rr++) {
                            float av = (kof == 0) ? a[rr].x : (kof == 1) ? a[rr].y
                                     : (kof == 2) ? a[rr].z : a[rr].w;
                            acc[rr][0] = fmaf(-av, b0, acc[rr][0]);
                            acc[rr][1] = fmaf(-av, b1, acc[rr][1]);
                            acc[rr][2] = fmaf(-av, b2, acc[rr][2]);
                            acc[rr][3] = fmaf(-av, b3, acc[rr][3]);
                        }
                    }
                }
            }

            // store chunk; chunk 0 rows 0..63 also seed the LDS diag tile
            if (vA) {
#pragma unroll
                for (int rr = 0; rr < 8; rr++)
                    *(float4*)(Cb + (size_t)(gi0 + rr) * NA + jb + cg*4) =
                        make_float4(acc[rr][0], acc[rr][1], acc[rr][2], acc[rr][3]);
            }
            if (ch == 0 && rg < 8) {
#pragma unroll
                for (int rr = 0; rr < 8; rr++)
#pragma unroll
                    for (int cc = 0; cc < 4; cc++)
                        D[(rg*8 + rr) * 65 + cg*4 + cc] = acc[rr][cc];
            }
        }
        __threadfence();
        __syncthreads();

        // ---- Phase A2: panel row preload (rows on tid 64..; reads phase-U stores)
        const int m = mp - 64;
        float rv[64];
        const int r = tid - 64;
        if (r >= 0 && r < m) {
            const float4* rp = (const float4*)(Cb + (size_t)(jb + 64 + r) * NA + jb);
#pragma unroll
            for (int q = 0; q < 16; q++) {
                float4 v = rp[q];
                rv[4*q] = v.x; rv[4*q+1] = v.y; rv[4*q+2] = v.z; rv[4*q+3] = v.w;
            }
        }

        // ---- Phase B: wave 0 register-resident symmetric elimination
        if (tid < 64) {
            const int t = tid;
            float cl[64];
#pragma unroll
            for (int i = 0; i < 64; i++) cl[i] = (i >= t) ? D[i * 65 + t] : D[t * 65 + i];
#pragma unroll
            for (int k = 0; k < 64; k++) {
                float pivot = rl(cl[k], k);
                float invp = 1.0f / pivot;
                float factor = (t > k) ? (cl[k] * invp) : 0.0f;
#pragma unroll
                for (int i = k + 1; i < 64; i++) {
                    float bc = rl(cl[i], k);
                    cl[i] -= bc * factor;
                }
            }
            float rs = 1.0f / sqrtf(cl[t]);
            invd[t] = rs;
#pragma unroll
            for (int i = 0; i < 64; i++)
                if (i >= t) D[i * 65 + t] = cl[i] * rs;
        }
        __syncthreads();

        // ---- Phase B2: build DT (strict lower, zero pad) + store L diag (lower)
#pragma unroll
        for (int e = 0; e < 8; e++) {
            int f = e * 512 + tid;
            int row = f >> 6, cc = f & 63;
            float v = D[row * 65 + cc];
            DT[row * 64 + cc] = (cc < row) ? v : 0.f;
            if (cc <= row) Cb[(size_t)(jb + row) * NA + jb + cc] = v;
        }
        __syncthreads();

        // ---- Phase C: row-owned trsm, store L21 panel
        if (r >= 0 && r < m) {
#pragma unroll
            for (int k = 0; k < 64; k++) {
                float acc = rv[k];
                const float4* Lr = (const float4*)(DT + k * 64);
                const int k4 = k >> 2;
#pragma unroll
                for (int t4 = 0; t4 < k4; t4++) {
                    float4 Lv = Lr[t4];
                    acc -= Lv.x * rv[4*t4] + Lv.y * rv[4*t4+1] + Lv.z * rv[4*t4+2] + Lv.w * rv[4*t4+3];
                }
#pragma unroll
                for (int tt = k4 * 4; tt < k; tt++) acc -= DT[k * 64 + tt] * rv[tt];
                rv[k] = acc * invd[k];
            }
            float4* rp = (float4*)(Cb + (size_t)(jb + 64 + r) * NA + jb);
#pragma unroll
            for (int q = 0; q < 16; q++)
                rp[q] = make_float4(rv[4*q], rv[4*q+1], rv[4*q+2], rv[4*q+3]);
        }
        __threadfence();
        __syncthreads();
    }
}

// ---------------------------------------------------------------- K3: solve + outputs
__global__ void __launch_bounds__(512, 1) k_solve(const float* __restrict__ C,
                                                  const float* __restrict__ chiA,
                                                  const float* __restrict__ Qtot,
                                                  float* __restrict__ out, int B) {
    int b = blockIdx.x;
    const float* Cb = C + (size_t)b * NN;
    int tid = threadIdx.x;
    __shared__ float D[64 * 65];
    __shared__ float r1[NA], r2[NA];
    __shared__ float pb1[4][NA], pb2[4][NA];
    __shared__ float red[16];
    __shared__ float muS;

    r1[tid] = chiA[b * NA + tid];
    r2[tid] = 1.0f;

    const int sub = tid & 7;        // forward: 8 lanes per row
    const int rowg = tid >> 3;

    // -------- forward: L y = r
    for (int j = 0; j < 8; j++) {
        const int jb = j * 64;
        __syncthreads();
#pragma unroll
        for (int e = 0; e < 8; e++) {
            int f = e * 512 + tid;
            int row = f >> 6, cc = f & 63;
            D[row * 65 + cc] = Cb[(size_t)(jb + row) * NA + jb + cc];
        }
        __syncthreads();
        if (tid < 128) {
            int lane = tid & 63;
            float* vv = (tid < 64) ? r1 : r2;
            float val = vv[jb + lane];
            float idg = 1.0f / D[lane * 65 + lane];
#pragma unroll
            for (int k = 0; k < 64; k++) {
                float yk = rl(val, k) * rl(idg, k);
                if (lane == k) vv[jb + k] = yk;
                float lv = (lane > k) ? D[lane * 65 + k] : 0.f;
                val -= lv * yk;
            }
        }
        __syncthreads();
#pragma unroll
        for (int p = 0; p < 7; p++) {
            int g = jb + 64 + p * 64 + rowg;
            if (g < NA) {
                const float4* Lr = (const float4*)(Cb + (size_t)g * NA + jb + sub * 8);
                float4 a0 = Lr[0], a1 = Lr[1];
                int y0 = jb + sub * 8;
                float d1 = a0.x*r1[y0]   + a0.y*r1[y0+1] + a0.z*r1[y0+2] + a0.w*r1[y0+3]
                         + a1.x*r1[y0+4] + a1.y*r1[y0+5] + a1.z*r1[y0+6] + a1.w*r1[y0+7];
                float d2 = a0.x*r2[y0]   + a0.y*r2[y0+1] + a0.z*r2[y0+2] + a0.w*r2[y0+3]
                         + a1.x*r2[y0+4] + a1.y*r2[y0+5] + a1.z*r2[y0+6] + a1.w*r2[y0+7];
                d1 += __shfl_xor(d1, 1); d2 += __shfl_xor(d2, 1);
                d1 += __shfl_xor(d1, 2); d2 += __shfl_xor(d2, 2);
                d1 += __shfl_xor(d1, 4); d2 += __shfl_xor(d2, 4);
                if (sub == 0) { r1[g] -= d1; r2[g] -= d2; }
            }
        }
    }

    // -------- backward: L^T x = y
    const int ii = tid & 127;
    const int gg = tid >> 7;
    for (int j = 7; j >= 0; j--) {
        const int jb = j * 64;
        __syncthreads();
#pragma unroll
        for (int e = 0; e < 8; e++) {
            int f = e * 512 + tid;
            int row = f >> 6, cc = f & 63;
            D[row * 65 + cc] = Cb[(size_t)(jb + row) * NA + jb + cc];
        }
        __syncthreads();
        if (tid < 128) {
            int lane = tid & 63;
            float* vv = (tid < 64) ? r1 : r2;
            float val = vv[jb + lane];
            float idg = 1.0f / D[lane * 65 + lane];
#pragma unroll
            for (int k = 63; k >= 0; k--) {
                float xk = rl(val, k) * rl(idg, k);
                if (lane == k) vv[jb + k] = xk;
                float lv = (lane < k) ? D[k * 65 + lane] : 0.f;
                val -= lv * xk;
            }
        }
        __syncthreads();
        if (jb > 0) {
            const int nf4 = jb >> 2;
            float4 s1 = make_float4(0.f,0.f,0.f,0.f), s2 = make_float4(0.f,0.f,0.f,0.f);
            if (ii < nf4) {
#pragma unroll
                for (int gq = 0; gq < 16; gq++) {
                    int g = jb + gg * 16 + gq;
                    float x1 = r1[g], x2 = r2[g];
                    float4 Lv = *(const float4*)(Cb + (size_t)g * NA + ii * 4);
                    s1.x += Lv.x * x1; s1.y += Lv.y * x1; s1.z += Lv.z * x1; s1.w += Lv.w * x1;
                    s2.x += Lv.x * x2; s2.y += Lv.y * x2; s2.z += Lv.z * x2; s2.w += Lv.w * x2;
                }
            }
            *(float4*)(&pb1[gg][ii * 4]) = s1;
            *(float4*)(&pb2[gg][ii * 4]) = s2;
            __syncthreads();
            if (tid < jb) {
                r1[tid] -= pb1[0][tid] + pb1[1][tid] + pb1[2][tid] + pb1[3][tid];
                r2[tid] -= pb2[0][tid] + pb2[1][tid] + pb2[2][tid] + pb2[3][tid];
            }
        }
    }
    __syncthreads();

    // -------- mu, q, energy: e = 0.5*chi'q - 0.5*mu*Q
    float s1p = r1[tid], s2p = r2[tid];
#pragma unroll
    for (int off = 1; off < 64; off <<= 1) {
        s1p += __shfl_xor(s1p, off);
        s2p += __shfl_xor(s2p, off);
    }
    if ((tid & 63) == 0) { red[tid >> 6] = s1p; red[8 + (tid >> 6)] = s2p; }
    __syncthreads();
    if (tid == 0) {
        float s1 = 0.f, s2 = 0.f;
#pragma unroll
        for (int wv = 0; wv < 8; wv++) { s1 += red[wv]; s2 += red[8 + wv]; }
        muS = -(Qtot[b] + s1) / s2;
    }
    __syncthreads();
    float mu = muS;
    float qv = -r1[tid] - mu * r2[tid];
    out[B + (size_t)b * NA + tid] = qv;

    float eacc = chiA[b * NA + tid] * qv;
#pragma unroll
    for (int off = 1; off < 64; off <<= 1) eacc += __shfl_xor(eacc, off);
    __syncthreads();
    if ((tid & 63) == 0) red[tid >> 6] = eacc;
    __syncthreads();
    if (tid == 0) {
        float e = 0.f;
#pragma unroll
        for (int wv = 0; wv < 8; wv++) e += red[wv];
        out[b] = 0.5f * e - 0.5f * mu * Qtot[b];
    }
}

// ---------------------------------------------------------------- host launch
extern "C" void kernel_launch(void* const* d_in, const int* in_sizes, int n_in,
                              void* d_out, int out_size, void* d_ws, size_t ws_size,
                              hipStream_t stream) {
    const int B = in_sizes[3];          // 128 molecules
    const int N = in_sizes[2];          // 65536 atoms
    const float* feats = (const float*)d_in[0];
    const float* pos   = (const float*)d_in[1];
    const int*   type  = (const int*)d_in[2];
    const float* Qt    = (const float*)d_in[3];
    const float* w     = (const float*)d_in[4];
    const float* hard  = (const float*)d_in[5];
    const float* sig   = (const float*)d_in[6];
    float* out = (float*)d_out;
    float* ws  = (float*)d_ws;

    float* C    = ws;                       // B * 512 * 512 (holds L; upper never touched)
    float* chi  = ws + (size_t)B * NN;      // N
    float* diag = chi + N;                  // N
    float* sigA = diag + N;                 // N

    k_pre<<<(N + 255) / 256, 256, 0, stream>>>(feats, w, type, hard, sig, chi, diag, sigA, N);
    k_chol<<<B, 512, 0, stream>>>(pos, sigA, diag, C);
    k_solve<<<B, 512, 0, stream>>>(C, chi, Qt, out, B);
}